// Round 3
// baseline (893.053 us; speedup 1.0000x reference)
//
#include <hip/hip_runtime.h>

// Problem: B=256, C=2048, N=H*W=288, K=6, fp32.
// out[b,c,k] = mean over {n: argmin_k dist(x[b,:,n], cluster_k)} of x[b,c,n], 0 if empty.
// R3: phase-1 restructured for MLP — clusters staged in LDS (cl reads move from
// vmcnt to lgkmcnt so x prefetches stay in flight), explicit 4-deep double-buffered
// x prefetch, f32 accumulation (128 terms/acc) with f64 fold+argmin.
// Wave w owns c === w (mod 16); lane owns n-group {4l..4l+3} (+ n=256+l for l<32).

#define NB 256
#define NC 2048
#define NN 288
#define NK 6
#define NT 1024

__global__ __launch_bounds__(NT) void cluster_kernel(
    const float* __restrict__ x,
    const float* __restrict__ cl,
    float* __restrict__ out)
{
    __shared__ float cls[NK * NC];          // 48 KB, [k][c]
    __shared__ float part[4][NK][NN + 1];   // 27.7 KB, [q][k][n] (+1 pad)
    __shared__ double cnorm_s[NK];
    __shared__ unsigned assign_u[NN / 4];   // assignment bytes, 4 n per word
    __shared__ int counts[NK];
    __shared__ float inv_s[NK];

    const int tid = threadIdx.x;
    const int w = tid >> 6;
    const int lane = tid & 63;
    const int b = blockIdx.x;
    const float* xb = x + (size_t)b * (size_t)(NC * NN);

    if (tid < NK) counts[tid] = 0;

    // ---- stage clusters into LDS (coalesced float4) ----
    {
        const float4* src = (const float4*)cl;
        float4* dst = (float4*)cls;
#pragma unroll
        for (int t = 0; t < 3; ++t) dst[tid + NT * t] = src[tid + NT * t];
    }
    // ---- cnorm in f64: waves 0..5, one k each ----
    if (w < NK) {
        double s = 0.0;
#pragma unroll 4
        for (int c = lane; c < NC; c += 64) {
            double d = (double)cl[w * NC + c];
            s += d * d;
        }
#pragma unroll
        for (int off = 1; off < 64; off <<= 1) s += __shfl_xor(s, off, 64);
        if (lane == 0) cnorm_s[w] = s;
    }
    __syncthreads();

    // ---------------- Phase 1: dot[n][k] = sum_c x[b,c,n] * cl[k][c] ----------------
    float acc[4][NK];   // n = 4*lane + r
    float acct[NK];     // tail n = 256 + lane (lanes < 32)
#pragma unroll
    for (int r = 0; r < 4; ++r)
#pragma unroll
        for (int k = 0; k < NK; ++k) acc[r][k] = 0.f;
#pragma unroll
    for (int k = 0; k < NK; ++k) acct[k] = 0.f;

    const bool tl = lane < 32;
    float4 buf[4];
    float buft[4] = {0.f, 0.f, 0.f, 0.f};

    // prologue: chunk 0 (c = w + 16u)
#pragma unroll
    for (int u = 0; u < 4; ++u) {
        const int c = w + 16 * u;
        buf[u] = *(const float4*)(xb + (size_t)c * NN + 4 * lane);
    }
    if (tl) {
#pragma unroll
        for (int u = 0; u < 4; ++u) {
            const int c = w + 16 * u;
            buft[u] = xb[(size_t)c * NN + 256 + lane];
        }
    }

    for (int t = 0; t < 32; ++t) {
        float4 cur[4];
        float curt[4];
#pragma unroll
        for (int u = 0; u < 4; ++u) { cur[u] = buf[u]; curt[u] = buft[u]; }

        if (t < 31) {
#pragma unroll
            for (int u = 0; u < 4; ++u) {
                const int c = w + 64 * (t + 1) + 16 * u;
                buf[u] = *(const float4*)(xb + (size_t)c * NN + 4 * lane);
            }
            if (tl) {
#pragma unroll
                for (int u = 0; u < 4; ++u) {
                    const int c = w + 64 * (t + 1) + 16 * u;
                    buft[u] = xb[(size_t)c * NN + 256 + lane];
                }
            }
        }

#pragma unroll
        for (int u = 0; u < 4; ++u) {
            const int c = w + 64 * t + 16 * u;   // wave-uniform -> LDS broadcast reads
            float ck[NK];
#pragma unroll
            for (int k = 0; k < NK; ++k) ck[k] = cls[k * NC + c];
#pragma unroll
            for (int k = 0; k < NK; ++k) {
                acc[0][k] += cur[u].x * ck[k];
                acc[1][k] += cur[u].y * ck[k];
                acc[2][k] += cur[u].z * ck[k];
                acc[3][k] += cur[u].w * ck[k];
                acct[k]  += curt[u] * ck[k];
            }
        }
    }

    // ---- fold 16 wave-slices into 4 LDS partials: part[w&3] over stages w>>2 ----
    const int q = w & 3;
    const int stage = w >> 2;
    if (stage == 0) {
#pragma unroll
        for (int r = 0; r < 4; ++r)
#pragma unroll
            for (int k = 0; k < NK; ++k) part[q][k][4 * lane + r] = acc[r][k];
        if (tl) {
#pragma unroll
            for (int k = 0; k < NK; ++k) part[q][k][256 + lane] = acct[k];
        }
    }
    __syncthreads();
    if (stage == 1) {
#pragma unroll
        for (int r = 0; r < 4; ++r)
#pragma unroll
            for (int k = 0; k < NK; ++k) part[q][k][4 * lane + r] += acc[r][k];
        if (tl) {
#pragma unroll
            for (int k = 0; k < NK; ++k) part[q][k][256 + lane] += acct[k];
        }
    }
    __syncthreads();
    if (stage == 2) {
#pragma unroll
        for (int r = 0; r < 4; ++r)
#pragma unroll
            for (int k = 0; k < NK; ++k) part[q][k][4 * lane + r] += acc[r][k];
        if (tl) {
#pragma unroll
            for (int k = 0; k < NK; ++k) part[q][k][256 + lane] += acct[k];
        }
    }
    __syncthreads();
    if (stage == 3) {
#pragma unroll
        for (int r = 0; r < 4; ++r)
#pragma unroll
            for (int k = 0; k < NK; ++k) part[q][k][4 * lane + r] += acc[r][k];
        if (tl) {
#pragma unroll
            for (int k = 0; k < NK; ++k) part[q][k][256 + lane] += acct[k];
        }
    }
    __syncthreads();

    // ---- argmin_k (||c_k||^2 - 2 dot); strict < == numpy first-min tie-break ----
    if (tid < NN) {
        double best = 1e300;
        int bi = 0;
#pragma unroll
        for (int k = 0; k < NK; ++k) {
            double d = (double)part[0][k][tid] + (double)part[1][k][tid]
                     + (double)part[2][k][tid] + (double)part[3][k][tid];
            double sc = cnorm_s[k] - 2.0 * d;
            if (sc < best) { best = sc; bi = k; }
        }
        ((unsigned char*)assign_u)[tid] = (unsigned char)bi;
        atomicAdd(&counts[bi], 1);
    }
    __syncthreads();
    if (tid < NK) inv_s[tid] = counts[tid] > 0 ? 1.0f / (float)counts[tid] : 0.0f;
    __syncthreads();

    // -------- Phase 2: 16 lanes per c, 4 c per wave-iter; 6 shuffles per c --------
    const int sub = lane >> 4;    // which of 4 c this lane serves
    const int sl = lane & 15;     // sub-lane within the 16-lane group
    float* outb = out + (size_t)b * (size_t)(NC * NK);

    for (int cb = 4 * w; cb < NC; cb += 4 * (NT / 64)) {
        const int c = cb + sub;
        const float* row = xb + (size_t)c * NN;
        float a[NK];
#pragma unroll
        for (int k = 0; k < NK; ++k) a[k] = 0.f;

#pragma unroll
        for (int t = 0; t < 4; ++t) {
            const int g = sl + 16 * t;                 // float4-group, n = 4g..4g+3
            float4 v = *(const float4*)(row + 4 * g);
            unsigned am = assign_u[g];
            float vv[4] = {v.x, v.y, v.z, v.w};
#pragma unroll
            for (int r = 0; r < 4; ++r) {
                int ar = (int)((am >> (8 * r)) & 0xffu);
#pragma unroll
                for (int k = 0; k < NK; ++k) a[k] += (ar == k) ? vv[r] : 0.f;
            }
        }
        if (sl < 8) {   // remainder groups 64..71 (n = 256..287)
            const int g = 64 + sl;
            float4 v = *(const float4*)(row + 4 * g);
            unsigned am = assign_u[g];
            float vv[4] = {v.x, v.y, v.z, v.w};
#pragma unroll
            for (int r = 0; r < 4; ++r) {
                int ar = (int)((am >> (8 * r)) & 0xffu);
#pragma unroll
                for (int k = 0; k < NK; ++k) a[k] += (ar == k) ? vv[r] : 0.f;
            }
        }

        // butterfly within each 16-lane group
#pragma unroll
        for (int off = 1; off < 16; off <<= 1) {
#pragma unroll
            for (int k = 0; k < NK; ++k) a[k] += __shfl_xor(a[k], off, 64);
        }

        if (sl < NK) {
            float val = a[0];
            if (sl == 1) val = a[1];
            else if (sl == 2) val = a[2];
            else if (sl == 3) val = a[3];
            else if (sl == 4) val = a[4];
            else if (sl == 5) val = a[5];
            outb[(size_t)c * NK + sl] = val * inv_s[sl];
        }
    }
}

extern "C" void kernel_launch(void* const* d_in, const int* in_sizes, int n_in,
                              void* d_out, int out_size, void* d_ws, size_t ws_size,
                              hipStream_t stream) {
    const float* x = (const float*)d_in[0];
    const float* clusters = (const float*)d_in[1];
    float* out = (float*)d_out;
    hipLaunchKernelGGL(cluster_kernel, dim3(NB), dim3(NT), 0, stream,
                       x, clusters, out);
}